// Round 8
// baseline (177.432 us; speedup 1.0000x reference)
//
#include <hip/hip_runtime.h>

// StateSpaceLayer: out[b,t,r,c] = sum_{j<=t} A[r]^(t-j) * x[b,j,r,c]
// == linear recurrence out[t] = A[r]*out[t-1] + x[t] along seq.
// Shapes: x (4,512,64,64) f32, A (64,) f32, out (4,512,64,64) f32.
//
// V8: single-kernel decoupled chunk scan with PLANE-CONTIGUOUS access.
//   Evidence: V1/V2/V6b/V7 (all block-per-(b,r)) tie at ~82us -> the
//   invariant 256B@16KB-stride DRAM pattern is the limit (~62% of the
//   one-pass floor; sequential fills hit 80% of peak on the same pass).
//   Geometry: block = (b, time-chunk m of 32 steps, plane-quarter q).
//   256 blocks x 1024 thr, 4KB contiguous bursts, all co-resident.
//   Cross-block carry fixes vs V3/V4/V5 failures:
//     - ordinary launch (coop cost +200us in V3)
//     - single kernel (V4's ~8us/launch gaps)
//     - lean spin: ONE wave, one flag/lane, s_sleep (V5: 512thr x 63flags)
//     - lookback: fixed-trip fully-unrolled BRANCHLESS masked Horner
//       (V5/V3: runtime-trip loop = serial latency), volume 60KB/block.
//   Flag/fence protocol identical to V5 (correctness-proven on HW).

#define B_    4
#define SEQ_  512
#define D_    64
#define PQ_   1024            // float4 per 16 KB plane
#define NM_   16              // time-chunks
#define CT_   32              // timesteps per chunk
#define NQ_   4               // plane quarters
#define QS_   256             // float4 slots per quarter
#define NSUB_ 4               // sub-chunks per chunk
#define CH_   8               // timesteps per sub-chunk
#define NTHR_ 1024
#define GRID_ (B_ * NM_ * NQ_)    // 256 blocks
#define NFLAGS_ (B_ * NQ_ * NM_)  // 256 flags

typedef float f32x4 __attribute__((ext_vector_type(4)));

__global__ __launch_bounds__(NTHR_, 1) void ssm_dlb2(
    const float* __restrict__ x, const float* __restrict__ A,
    float* __restrict__ out, float* __restrict__ E,
    int* __restrict__ flags)
{
    __shared__ f32x4 Esub[NSUB_][QS_];     // 16 KB sub-chunk end states

    const int blk = blockIdx.x;            // ((b*NM_ + m)*NQ_ + q)
    const int q   = blk & (NQ_ - 1);
    const int m   = (blk >> 2) & (NM_ - 1);
    const int b   = blk >> 6;
    const int tid = threadIdx.x;
    const int ls  = tid & (QS_ - 1);       // slot within quarter
    const int sub = tid >> 8;              // sub-chunk 0..3
    const int slot = q * QS_ + ls;         // float4 slot in plane
    const int r   = slot >> 4;             // decay row

    const float a  = fmaxf(A[r], 1e-6f);   // clip like reference (EPS=1e-6)
    const float a2 = a * a, a4 = a2 * a2, a8 = a4 * a4;
    const float a16 = a8 * a8, a32 = a16 * a16;

    const int j0 = m * CT_ + sub * CH_;
    const f32x4* xp = (const f32x4*)x + (size_t)(b * SEQ_ + j0) * PQ_ + slot;
    f32x4*       op = (f32x4*)out     + (size_t)(b * SEQ_ + j0) * PQ_ + slot;

    // Phase 1: local scan of 8 timesteps (4 KB contiguous bursts per instr).
    f32x4 loc[CH_];
    float s0 = 0.f, s1 = 0.f, s2 = 0.f, s3 = 0.f;
    #pragma unroll
    for (int t = 0; t < CH_; ++t) {
        f32x4 v = __builtin_nontemporal_load(xp + (size_t)t * PQ_);
        s0 = fmaf(s0, a, v.x);
        s1 = fmaf(s1, a, v.y);
        s2 = fmaf(s2, a, v.z);
        s3 = fmaf(s3, a, v.w);
        loc[t].x = s0; loc[t].y = s1; loc[t].z = s2; loc[t].w = s3;
    }

    // In-block scan over the 4 sub-chunks.
    f32x4 e_end; e_end.x = s0; e_end.y = s1; e_end.z = s2; e_end.w = s3;
    Esub[sub][ls] = e_end;
    __syncthreads();

    // C_sub = Horner over sub' < sub with multiplier a^8 (branchless masked).
    float c0 = 0.f, c1 = 0.f, c2 = 0.f, c3 = 0.f;
    #pragma unroll
    for (int i = 0; i < NSUB_ - 1; ++i) {
        const bool use = (i < sub);
        f32x4 e = Esub[i][ls];
        const float w = use ? a8 : 1.0f;
        c0 = fmaf(c0, w, use ? e.x : 0.f);
        c1 = fmaf(c1, w, use ? e.y : 0.f);
        c2 = fmaf(c2, w, use ? e.z : 0.f);
        c3 = fmaf(c3, w, use ? e.w : 0.f);
    }

    // Publish block aggregate G_m = C_3*a^8 + L_3 (sub-3 threads own it).
    if (m < NM_ - 1 && sub == NSUB_ - 1) {
        f32x4 g;
        g.x = fmaf(c0, a8, s0);
        g.y = fmaf(c1, a8, s1);
        g.z = fmaf(c2, a8, s2);
        g.w = fmaf(c3, a8, s3);
        ((f32x4*)E)[(size_t)(b * NM_ + m) * PQ_ + slot] = g;
    }
    __syncthreads();                       // publish stores drained (vmcnt 0)
    if (m < NM_ - 1 && tid == 0) {
        __threadfence();                   // release E data device-wide
        __hip_atomic_store(&flags[(b * NQ_ + q) * NM_ + m], 1,
                           __ATOMIC_RELEASE, __HIP_MEMORY_SCOPE_AGENT);
    }

    // Cross-block carry CB = masked Horner over predecessor aggregates (a^32).
    float cb0 = 0.f, cb1 = 0.f, cb2 = 0.f, cb3 = 0.f;
    if (m > 0) {
        if (tid < 64) {                    // ONE wave polls, one flag per lane
            const int mp = tid;
            if (mp < m) {
                while (__hip_atomic_load(&flags[(b * NQ_ + q) * NM_ + mp],
                       __ATOMIC_RELAXED, __HIP_MEMORY_SCOPE_AGENT) == 0) {
                    __builtin_amdgcn_s_sleep(2);
                }
            }
        }
        __syncthreads();                   // all threads see "flags ready"
        __threadfence();                   // acquire: invalidate stale lines

        const f32x4* Eb = (const f32x4*)E + (size_t)(b * NM_) * PQ_ + slot;
        #pragma unroll
        for (int mp = 0; mp < NM_ - 1; ++mp) {   // fixed trip, fully unrolled
            const bool use = (mp < m);
            f32x4 e = Eb[(size_t)mp * PQ_];      // select-after-load: safe
            const float w = use ? a32 : 1.0f;
            cb0 = fmaf(cb0, w, use ? e.x : 0.f);
            cb1 = fmaf(cb1, w, use ? e.y : 0.f);
            cb2 = fmaf(cb2, w, use ? e.z : 0.f);
            cb3 = fmaf(cb3, w, use ? e.w : 0.f);
        }
    }

    // Total carry entering this sub-chunk: S_in = C_sub + CB * a^(8*sub).
    float a8p = 1.f;
    #pragma unroll
    for (int i = 0; i < NSUB_ - 1; ++i) a8p = (i < sub) ? a8p * a8 : a8p;
    c0 = fmaf(cb0, a8p, c0);
    c1 = fmaf(cb1, a8p, c1);
    c2 = fmaf(cb2, a8p, c2);
    c3 = fmaf(cb3, a8p, c3);

    // Phase 3: fixup + contiguous NT stores. out[j0+t] = loc[t] + S_in*a^(t+1)
    float p = a;
    #pragma unroll
    for (int t = 0; t < CH_; ++t) {
        f32x4 o;
        o.x = fmaf(c0, p, loc[t].x);
        o.y = fmaf(c1, p, loc[t].y);
        o.z = fmaf(c2, p, loc[t].z);
        o.w = fmaf(c3, p, loc[t].w);
        __builtin_nontemporal_store(o, op + (size_t)t * PQ_);
        p *= a;
    }
}

// ---- Fallback (ws unusable): V7 block-per-(b,r) kernel (proven ~82us) ----
#define CHF_  8
#define NCHF_ (SEQ_ / CHF_)
#define NCQF_ (D_ / 4)
#define PADF_ (NCQF_ + 1)

__global__ __launch_bounds__(1024, 1) void ssm_fallback(
    const float* __restrict__ x, const float* __restrict__ A,
    float* __restrict__ out)
{
    __shared__ float4 Epad[NCHF_][PADF_];
    const int blk = blockIdx.x, bi = blk >> 6, r = blk & 63;
    const int tid = threadIdx.x, ch = tid >> 4, cq = tid & 15;
    const float a = fmaxf(A[r], 1e-6f);
    const size_t base = ((size_t)(bi * SEQ_ + ch * CHF_) * D_ + r) * D_ + cq * 4;
    const float4* xp = (const float4*)(x + base);
    f32x4*        op = (f32x4*)(out + base);
    const int js4 = (D_ * D_) / 4;
    float4 loc[CHF_];
    float s0 = 0.f, s1 = 0.f, s2 = 0.f, s3 = 0.f;
    #pragma unroll
    for (int t = 0; t < CHF_; ++t) {
        float4 v = xp[(size_t)t * js4];
        s0 = fmaf(s0, a, v.x); s1 = fmaf(s1, a, v.y);
        s2 = fmaf(s2, a, v.z); s3 = fmaf(s3, a, v.w);
        loc[t] = make_float4(s0, s1, s2, s3);
    }
    Epad[ch][cq] = make_float4(s0, s1, s2, s3);
    __syncthreads();
    const float a2 = a * a, a4 = a2 * a2, aL = a4 * a4;
    {
        const int w = tid >> 6, mm = tid & 63;
        float4 v = Epad[mm][w];
        float aw = aL;
        #pragma unroll
        for (int s = 0; s < 6; ++s) {
            const int d = 1 << s;
            float ux = __shfl_up(v.x, d, 64), uy = __shfl_up(v.y, d, 64);
            float uz = __shfl_up(v.z, d, 64), uw = __shfl_up(v.w, d, 64);
            if (mm >= d) {
                v.x = fmaf(aw, ux, v.x); v.y = fmaf(aw, uy, v.y);
                v.z = fmaf(aw, uz, v.z); v.w = fmaf(aw, uw, v.w);
            }
            aw *= aw;
        }
        Epad[mm][w] = v;
    }
    __syncthreads();
    float c0 = 0.f, c1 = 0.f, c2 = 0.f, c3 = 0.f;
    if (ch > 0) {
        float4 c4 = Epad[ch - 1][cq];
        c0 = c4.x; c1 = c4.y; c2 = c4.z; c3 = c4.w;
    }
    float p = a;
    #pragma unroll
    for (int t = 0; t < CHF_; ++t) {
        f32x4 o;
        o.x = fmaf(c0, p, loc[t].x); o.y = fmaf(c1, p, loc[t].y);
        o.z = fmaf(c2, p, loc[t].z); o.w = fmaf(c3, p, loc[t].w);
        __builtin_nontemporal_store(o, &op[(size_t)t * js4]);
        p *= a;
    }
}

extern "C" void kernel_launch(void* const* d_in, const int* in_sizes, int n_in,
                              void* d_out, int out_size, void* d_ws, size_t ws_size,
                              hipStream_t stream) {
    const float* x   = (const float*)d_in[0];
    const float* A   = (const float*)d_in[1];
    float*       out = (float*)d_out;

    const size_t eBytes = sizeof(float) * (size_t)B_ * NM_ * PQ_ * 4;  // 1 MB
    const size_t fBytes = sizeof(int) * (size_t)NFLAGS_;               // 1 KB

    if (d_ws != nullptr && ws_size >= eBytes + fBytes) {
        float* E     = (float*)d_ws;
        int*   flags = (int*)((char*)d_ws + eBytes);
        hipMemsetAsync(flags, 0, fBytes, stream);   // ws is re-poisoned hot
        hipLaunchKernelGGL(ssm_dlb2, dim3(GRID_), dim3(NTHR_), 0, stream,
                           x, A, out, E, flags);
    } else {
        hipLaunchKernelGGL(ssm_fallback, dim3(B_ * D_), dim3(NTHR_),
                           0, stream, x, A, out);
    }
}

// Round 9
// 81.866 us; speedup vs baseline: 2.1673x; 2.1673x over previous
//
#include <hip/hip_runtime.h>

// StateSpaceLayer: out[b,t,r,c] = sum_{j<=t} A[r]^(t-j) * x[b,j,r,c]
// == linear recurrence out[t] = A[r]*out[t-1] + x[t] along seq.
// Shapes: x (4,512,64,64) f32, A (64,) f32, out (4,512,64,64) f32.
//
// V9: break phase lockstep — 512 blocks x 512 threads, 2 blocks/CU.
//   Closed directions (measured): cross-block carry is dead on this chip
//   (V3 coop +200us, V4 multi-kernel gaps, V5 fat-spin kernel 180us,
//   V8 lean-spin kernel 112us — the fence/flag protocol alone costs
//   ~95us). Intra-block micro-opts are all neutral (V2 float4, V6b
//   pin+NT, V7 parallel scan): ~82us = ~17us kernel + ~65us harness.
//   Last untested variable: with 1024-thr blocks at 1/CU, block-wide
//   barriers put every CU in the same phase (read burst -> bubble ->
//   write burst) with nothing resident to fill the bubble.
//   Fix: block = (b, r, column-half): 512 blocks x 512 thr = 2
//   independent blocks/CU. The seq axis stays whole per block (scan is
//   still purely intra-block; the column split carries nothing). The two
//   resident blocks interleave phases: one block's barrier+carry bubble
//   is covered by the other's loads/stores; DRAM sees mixed read/write.

#define B_    4
#define SEQ_  512
#define D_    64
#define CH_   8                  // timesteps per thread
#define NCH_  (SEQ_ / CH_)       // 64 chunks == 64 lanes in the KS scan
#define NCQH_ 8                  // float4 columns per half (32 cols)
#define NTHR_ (NCH_ * NCQH_)     // 512 threads = 8 waves
#define PAD_  (NCQH_ + 1)        // 9: de-conflict the column-major read
#define GRID_ (B_ * D_ * 2)      // 512 blocks -> 2 per CU

typedef float f32x4 __attribute__((ext_vector_type(4)));

__global__ __launch_bounds__(NTHR_, 4) void ssm_scan_kernel(
    const float* __restrict__ x, const float* __restrict__ A,
    float* __restrict__ out)
{
    __shared__ float4 Epad[NCH_][PAD_];   // 9 KB: chunk-end states (padded)

    const int blk = blockIdx.x;          // (bi*64 + r)*2 + h
    const int h   = blk & 1;             // column half
    const int r   = (blk >> 1) & 63;     // row (decay) index
    const int bi  = blk >> 7;            // batch index
    const int tid = threadIdx.x;
    const int ch  = tid >> 3;            // chunk id 0..63
    const int cq  = tid & 7;             // float4 column within half 0..7

    const float a = fmaxf(A[r], 1e-6f);  // clip like reference (EPS=1e-6)

    const int j0 = ch * CH_;
    // flat float index of x[bi, j0, r, (h*8+cq)*4]
    const size_t base = ((size_t)(bi * SEQ_ + j0) * D_ + r) * D_
                        + (h * NCQH_ + cq) * 4;
    const float4* xp = (const float4*)(x + base);
    f32x4*        op = (f32x4*)(out + base);
    const int jstride4 = (D_ * D_) / 4;  // 1024 float4 between timesteps

    // Phase 1: local scan of this chunk with zero initial state.
    float4 loc[CH_];
    float s0 = 0.f, s1 = 0.f, s2 = 0.f, s3 = 0.f;
    #pragma unroll
    for (int t = 0; t < CH_; ++t) {
        float4 v = xp[(size_t)t * jstride4];
        s0 = fmaf(s0, a, v.x);
        s1 = fmaf(s1, a, v.y);
        s2 = fmaf(s2, a, v.z);
        s3 = fmaf(s3, a, v.w);
        loc[t] = make_float4(s0, s1, s2, s3);
    }

    // Keep scan results pinned in VGPRs through the barriers (prevents the
    // compiler from legally re-loading x in phase 3).
    #pragma unroll
    for (int t = 0; t < CH_; ++t) {
        asm volatile("" : "+v"(loc[t].x), "+v"(loc[t].y),
                         "+v"(loc[t].z), "+v"(loc[t].w));
    }

    // Publish chunk-end state.
    Epad[ch][cq] = make_float4(s0, s1, s2, s3);
    __syncthreads();

    // a^CH_ (= a^8) via 3 squarings.
    const float a2 = a * a, a4 = a2 * a2, aL = a4 * a4;

    // Phase 2: wave-parallel weighted Kogge-Stone inclusive scan.
    // Wave w (0..7) owns float4-column cq=w; lane m owns chunk m.
    //   step s: I_m += aL^(2^s) * I_{m-2^s}
    {
        const int w = tid >> 6;          // wave id == column it scans
        const int m = tid & 63;          // lane == chunk index
        float4 v = Epad[m][w];
        float aw = aL;
        #pragma unroll
        for (int s = 0; s < 6; ++s) {
            const int d = 1 << s;
            float ux = __shfl_up(v.x, d, 64);
            float uy = __shfl_up(v.y, d, 64);
            float uz = __shfl_up(v.z, d, 64);
            float uw = __shfl_up(v.w, d, 64);
            if (m >= d) {
                v.x = fmaf(aw, ux, v.x);
                v.y = fmaf(aw, uy, v.y);
                v.z = fmaf(aw, uz, v.z);
                v.w = fmaf(aw, uw, v.w);
            }
            aw *= aw;
        }
        // Wave-exclusive column: no cross-wave hazard, no barrier needed
        // between this wave's read and write-back.
        Epad[m][w] = v;
    }
    __syncthreads();

    // Exclusive carry into chunk ch = inclusive scan at ch-1.
    float c0 = 0.f, c1 = 0.f, c2 = 0.f, c3 = 0.f;
    if (ch > 0) {
        float4 c4 = Epad[ch - 1][cq];
        c0 = c4.x; c1 = c4.y; c2 = c4.z; c3 = c4.w;
    }

    // Phase 3: fix up with carry and store (non-temporal: write-once data).
    float p = a;
    #pragma unroll
    for (int t = 0; t < CH_; ++t) {
        float4 l = loc[t];
        f32x4 o;
        o.x = fmaf(c0, p, l.x);
        o.y = fmaf(c1, p, l.y);
        o.z = fmaf(c2, p, l.z);
        o.w = fmaf(c3, p, l.w);
        __builtin_nontemporal_store(o, &op[(size_t)t * jstride4]);
        p *= a;
    }
}

extern "C" void kernel_launch(void* const* d_in, const int* in_sizes, int n_in,
                              void* d_out, int out_size, void* d_ws, size_t ws_size,
                              hipStream_t stream) {
    const float* x   = (const float*)d_in[0];
    const float* A   = (const float*)d_in[1];
    float*       out = (float*)d_out;

    dim3 grid(GRID_);              // 512 blocks = 2 per CU
    dim3 block(NTHR_);             // 512 threads = 8 waves
    hipLaunchKernelGGL(ssm_scan_kernel, grid, block, 0, stream, x, A, out);
}